// Round 1
// baseline (844.844 us; speedup 1.0000x reference)
//
#include <hip/hip_runtime.h>
#include <hip/hip_bf16.h>
#include <stdint.h>

typedef unsigned short u16;
typedef __attribute__((ext_vector_type(8))) __bf16 bf16x8;
typedef __attribute__((ext_vector_type(4))) float f32x4;

#define BATCH 8192
#define HID   2048
#define COMB  4096

__device__ __forceinline__ u16 f2bf(float f) {
  uint32_t u = __float_as_uint(f);
  u += 0x7fffu + ((u >> 16) & 1u);  // round-to-nearest-even
  return (u16)(u >> 16);
}
__device__ __forceinline__ float bf2f(u16 b) {
  return __uint_as_float(((uint32_t)b) << 16);
}
__device__ __forceinline__ float fsigmoid(float x) {
  return 1.0f / (1.0f + __expf(-x));
}
__device__ __forceinline__ float ftanh(float x) {
  return 1.0f - 2.0f / (__expf(2.0f * x) + 1.0f);
}
__device__ __forceinline__ void gload_lds16(const void* g, void* l) {
  __builtin_amdgcn_global_load_lds(
      (__attribute__((address_space(1))) void*)(uintptr_t)g,
      (__attribute__((address_space(3))) void*)(uintptr_t)l,
      16, 0, 0);
}

// ---- pack [x | h_prev] f32 -> A1 bf16 [8192][4096] ----
__global__ void pack_A_kernel(const float* __restrict__ x, const float* __restrict__ h,
                              u16* __restrict__ A1) {
  const size_t tid = (size_t)blockIdx.x * blockDim.x + threadIdx.x;  // 4M threads, 8 elems each
  const int r  = (int)(tid >> 9);
  const int c8 = (int)(tid & 511);
  const float* s = (c8 < 256) ? (x + (size_t)r * 2048 + (size_t)c8 * 8)
                              : (h + (size_t)r * 2048 + (size_t)(c8 - 256) * 8);
  const float4 v0 = ((const float4*)s)[0];
  const float4 v1 = ((const float4*)s)[1];
  const uint32_t p0 = (uint32_t)f2bf(v0.x) | ((uint32_t)f2bf(v0.y) << 16);
  const uint32_t p1 = (uint32_t)f2bf(v0.z) | ((uint32_t)f2bf(v0.w) << 16);
  const uint32_t p2 = (uint32_t)f2bf(v1.x) | ((uint32_t)f2bf(v1.y) << 16);
  const uint32_t p3 = (uint32_t)f2bf(v1.z) | ((uint32_t)f2bf(v1.w) << 16);
  *(uint4*)(A1 + tid * 8) = make_uint4(p0, p1, p2, p3);
}

// ---- transpose W [4096][2048] f32 -> dst [2048][4096] bf16 ----
__global__ void transpose_w_kernel(const float* __restrict__ src, u16* __restrict__ dst) {
  __shared__ float tile[32][33];
  const int n0 = blockIdx.x * 32;
  const int k0 = blockIdx.y * 32;
  const int tx = threadIdx.x, ty = threadIdx.y;  // 32 x 8
#pragma unroll
  for (int i = 0; i < 32; i += 8)
    tile[ty + i][tx] = src[(size_t)(k0 + ty + i) * 2048 + n0 + tx];
  __syncthreads();
#pragma unroll
  for (int i = 0; i < 32; i += 8)
    dst[(size_t)(n0 + ty + i) * 4096 + k0 + tx] = f2bf(tile[tx][ty + i]);
}

// ---- GEMM1: [x|h] @ [Wz ‖ Wr]  (M=8192, N=4096, K=4096), fused sigmoid epilogue ----
__global__ __launch_bounds__(256) void gemm_zr_kernel(
    const u16* __restrict__ A1, const u16* __restrict__ B1t,
    const float* __restrict__ h_prev, const float* __restrict__ b_z,
    const float* __restrict__ b_r, u16* __restrict__ zbuf, u16* __restrict__ RH) {
  __shared__ u16 Alds[128 * 64];
  __shared__ u16 Blds[128 * 64];
  const int t = threadIdx.x;
  const int l = t & 63, w = t >> 6;
  const int wm = w >> 1, wn = w & 1;
  const int bm = blockIdx.y, bn = blockIdx.x;

  f32x4 acc[4][4] = {};

  const int srow = t >> 3;         // 0..31
  const int scol = (t & 7) * 8;    // 0..56
  const size_t aBase = (size_t)(bm * 128 + srow) * COMB + scol;
  const size_t bBase = (size_t)(bn * 128 + srow) * COMB + scol;
  u16* ldsA = Alds + w * 512;
  u16* ldsB = Blds + w * 512;

  for (int kt = 0; kt < 64; ++kt) {
    const int ko = kt * 64;
#pragma unroll
    for (int i = 0; i < 4; ++i) {
      gload_lds16(A1 + aBase + (size_t)i * 32 * COMB + ko, ldsA + i * 2048);
      gload_lds16(B1t + bBase + (size_t)i * 32 * COMB + ko, ldsB + i * 2048);
    }
    __syncthreads();
#pragma unroll
    for (int ks = 0; ks < 2; ++ks) {
      const int kk = ks * 32 + (l >> 4) * 8;
      bf16x8 af[4], bb[4];
#pragma unroll
      for (int m = 0; m < 4; ++m)
        af[m] = *(const bf16x8*)(Alds + (wm * 64 + m * 16 + (l & 15)) * 64 + kk);
#pragma unroll
      for (int n = 0; n < 4; ++n)
        bb[n] = *(const bf16x8*)(Blds + (wn * 64 + n * 16 + (l & 15)) * 64 + kk);
#pragma unroll
      for (int m = 0; m < 4; ++m)
#pragma unroll
        for (int n = 0; n < 4; ++n)
          acc[m][n] = __builtin_amdgcn_mfma_f32_16x16x32_bf16(af[m], bb[n], acc[m][n], 0, 0, 0);
    }
    __syncthreads();
  }

  const int lc = l & 15;
  const int rowBase = bm * 128 + wm * 64 + (l >> 4) * 4;
  const int colBase = bn * 128 + wn * 64;
  if (colBase < 2048) {  // z-gate half (uniform per block)
#pragma unroll
    for (int n = 0; n < 4; ++n) {
      const int col = colBase + n * 16 + lc;
      const float bz = b_z[col];
#pragma unroll
      for (int m = 0; m < 4; ++m)
#pragma unroll
        for (int r = 0; r < 4; ++r) {
          const size_t idx = (size_t)(rowBase + m * 16 + r) * HID + col;
          zbuf[idx] = f2bf(fsigmoid(acc[m][n][r] + bz));
        }
    }
  } else {  // r-gate half: write r * h_prev as bf16
#pragma unroll
    for (int n = 0; n < 4; ++n) {
      const int col = colBase - 2048 + n * 16 + lc;
      const float br = b_r[col];
#pragma unroll
      for (int m = 0; m < 4; ++m)
#pragma unroll
        for (int r = 0; r < 4; ++r) {
          const size_t idx = (size_t)(rowBase + m * 16 + r) * HID + col;
          const float rv = fsigmoid(acc[m][n][r] + br);
          RH[idx] = f2bf(rv * h_prev[idx]);
        }
    }
  }
}

// ---- GEMM2: [x | r*h] @ Wn  (M=8192, N=2048, K=4096), fused tanh + GRU update ----
__global__ __launch_bounds__(256) void gemm_n_kernel(
    const u16* __restrict__ A1, const u16* __restrict__ RH, const u16* __restrict__ B2t,
    const float* __restrict__ h_prev, const float* __restrict__ b_n,
    const u16* __restrict__ zbuf, float* __restrict__ out) {
  __shared__ u16 Alds[128 * 64];
  __shared__ u16 Blds[128 * 64];
  const int t = threadIdx.x;
  const int l = t & 63, w = t >> 6;
  const int wm = w >> 1, wn = w & 1;
  const int bm = blockIdx.y, bn = blockIdx.x;

  f32x4 acc[4][4] = {};

  const int srow = t >> 3;
  const int scol = (t & 7) * 8;
  u16* ldsA = Alds + w * 512;
  u16* ldsB = Blds + w * 512;

  for (int kt = 0; kt < 64; ++kt) {
    const u16* aP;
    int ld, ko;
    if (kt < 32) { aP = A1; ld = COMB; ko = kt * 64; }      // x half
    else         { aP = RH; ld = HID;  ko = kt * 64 - 2048; }  // r*h half
#pragma unroll
    for (int i = 0; i < 4; ++i) {
      gload_lds16(aP + (size_t)(bm * 128 + i * 32 + srow) * ld + ko + scol, ldsA + i * 2048);
      gload_lds16(B2t + (size_t)(bn * 128 + i * 32 + srow) * COMB + kt * 64 + scol, ldsB + i * 2048);
    }
    __syncthreads();
#pragma unroll
    for (int ks = 0; ks < 2; ++ks) {
      const int kk = ks * 32 + (l >> 4) * 8;
      bf16x8 af[4], bb[4];
#pragma unroll
      for (int m = 0; m < 4; ++m)
        af[m] = *(const bf16x8*)(Alds + (wm * 64 + m * 16 + (l & 15)) * 64 + kk);
#pragma unroll
      for (int n = 0; n < 4; ++n)
        bb[n] = *(const bf16x8*)(Blds + (wn * 64 + n * 16 + (l & 15)) * 64 + kk);
#pragma unroll
      for (int m = 0; m < 4; ++m)
#pragma unroll
        for (int n = 0; n < 4; ++n)
          acc[m][n] = __builtin_amdgcn_mfma_f32_16x16x32_bf16(af[m], bb[n], acc[m][n], 0, 0, 0);
    }
    __syncthreads();
  }

  const int lc = l & 15;
  const int rowBase = bm * 128 + wm * 64 + (l >> 4) * 4;
  const int colBase = bn * 128 + wn * 64;
#pragma unroll
  for (int n = 0; n < 4; ++n) {
    const int col = colBase + n * 16 + lc;
    const float bnv = b_n[col];
#pragma unroll
    for (int m = 0; m < 4; ++m)
#pragma unroll
      for (int r = 0; r < 4; ++r) {
        const size_t idx = (size_t)(rowBase + m * 16 + r) * HID + col;
        const float nn = ftanh(acc[m][n][r] + bnv);
        const float z = bf2f(zbuf[idx]);
        const float hp = h_prev[idx];
        out[idx] = (1.0f - z) * hp + z * nn;
      }
  }
}

extern "C" void kernel_launch(void* const* d_in, const int* in_sizes, int n_in,
                              void* d_out, int out_size, void* d_ws, size_t ws_size,
                              hipStream_t stream) {
  const float* x  = (const float*)d_in[0];
  const float* h  = (const float*)d_in[1];
  const float* Wz = (const float*)d_in[2];
  const float* bz = (const float*)d_in[3];
  const float* Wr = (const float*)d_in[4];
  const float* br = (const float*)d_in[5];
  const float* Wn = (const float*)d_in[6];
  const float* bn = (const float*)d_in[7];
  float* out = (float*)d_out;

  char* ws = (char*)d_ws;
  u16* A1  = (u16*)(ws);                    // 8192*4096*2 = 67108864
  u16* RH  = (u16*)(ws + 67108864);         // 8192*2048*2 = 33554432
  u16* B1t = (u16*)(ws + 100663296);        // 4096*4096*2 = 33554432  ([Wz;Wr]^T)
  u16* B2t = (u16*)(ws + 134217728);        // 2048*4096*2 = 16777216  (Wn^T)
  u16* Z   = (u16*)(ws + 150994944);        // 8192*2048*2 = 33554432
  // total 184549376 bytes

  pack_A_kernel<<<16384, 256, 0, stream>>>(x, h, A1);
  dim3 tb(32, 8);
  transpose_w_kernel<<<dim3(64, 128), tb, 0, stream>>>(Wz, B1t);
  transpose_w_kernel<<<dim3(64, 128), tb, 0, stream>>>(Wr, B1t + (size_t)2048 * 4096);
  transpose_w_kernel<<<dim3(64, 128), tb, 0, stream>>>(Wn, B2t);

  gemm_zr_kernel<<<dim3(32, 64), 256, 0, stream>>>(A1, B1t, h, bz, br, Z, RH);
  gemm_n_kernel<<<dim3(16, 64), 256, 0, stream>>>(A1, RH, B2t, h, bn, Z, out);
}

// Round 2
// 581.471 us; speedup vs baseline: 1.4529x; 1.4529x over previous
//
#include <hip/hip_runtime.h>
#include <hip/hip_bf16.h>
#include <stdint.h>

typedef unsigned short u16;
typedef __attribute__((ext_vector_type(8))) __bf16 bf16x8;
typedef __attribute__((ext_vector_type(4))) float f32x4;

#define BATCH 8192
#define HID   2048
#define COMB  4096
#define NT    64   // K tiles of 64

__device__ __forceinline__ u16 f2bf(float f) {
  uint32_t u = __float_as_uint(f);
  u += 0x7fffu + ((u >> 16) & 1u);
  return (u16)(u >> 16);
}
__device__ __forceinline__ float bf2f(u16 b) {
  return __uint_as_float(((uint32_t)b) << 16);
}
__device__ __forceinline__ float fsigmoid(float x) { return 1.0f / (1.0f + __expf(-x)); }
__device__ __forceinline__ float ftanh(float x) { return 1.0f - 2.0f / (__expf(2.0f * x) + 1.0f); }

__device__ __forceinline__ void gload_lds16(const void* g, void* l) {
  __builtin_amdgcn_global_load_lds(
      (__attribute__((address_space(1))) void*)(uintptr_t)g,
      (__attribute__((address_space(3))) void*)(uintptr_t)l,
      16, 0, 0);
}

#define BARRIER() do { asm volatile("" ::: "memory"); __builtin_amdgcn_s_barrier(); asm volatile("" ::: "memory"); } while (0)
#define LGKM0()   asm volatile("s_waitcnt lgkmcnt(0)" ::: "memory")
#define VM6()     asm volatile("s_waitcnt vmcnt(6)" ::: "memory")
#define VM0()     asm volatile("s_waitcnt vmcnt(0)" ::: "memory")

// Stage one 128x64 bf16 half-tile: linear LDS dest (gload_lds requirement),
// inverse-XOR-swizzled per-lane GLOBAL source (rule #21: both-sides-or-neither).
// LDS(row, granule g) = global(row, g ^ (row&7)); granule = 16B.
__device__ __forceinline__ void stage_half(const u16* __restrict__ src, size_t ld,
                                           char* ldsHalf, int w, int l) {
  const int lrow = l >> 3;                    // 0..7 within 8-row group
  const int g    = (l & 7) ^ (lrow & 7);      // swizzled source granule
#pragma unroll
  for (int i = 0; i < 2; ++i) {
    const int r0 = (w * 2 + i) * 8;           // wave-uniform base row
    gload_lds16(src + (size_t)(r0 + lrow) * ld + g * 8, ldsHalf + r0 * 128);
  }
}

// Swizzled ds_read of one bf16x8 fragment. row in [0,128), kk multiple of 8.
__device__ __forceinline__ bf16x8 rd(const char* buf, int row, int kk) {
  const int byte = row * 128 + ((((kk >> 3) & 7) ^ (row & 7)) << 4);
  return *(const bf16x8*)(buf + byte);
}

#define MFMA_QUAD(MH, NH)                                                          \
  {                                                                                \
    _Pragma("unroll") for (int m_ = 0; m_ < 4; ++m_) {                             \
      _Pragma("unroll") for (int n_ = 0; n_ < 2; ++n_) {                           \
        _Pragma("unroll") for (int ks_ = 0; ks_ < 2; ++ks_) {                      \
          acc[(MH)*4 + m_][(NH)*2 + n_] = __builtin_amdgcn_mfma_f32_16x16x32_bf16( \
              af[(MH)*4 + m_][ks_], bb[(NH)*2 + n_][ks_],                          \
              acc[(MH)*4 + m_][(NH)*2 + n_], 0, 0, 0);                             \
        } } }                                                                      \
  }

// ---- pack [x | h_prev] f32 -> A1 bf16 [8192][4096] ----
__global__ void pack_A_kernel(const float* __restrict__ x, const float* __restrict__ h,
                              u16* __restrict__ A1) {
  const size_t tid = (size_t)blockIdx.x * blockDim.x + threadIdx.x;
  const int r  = (int)(tid >> 9);
  const int c8 = (int)(tid & 511);
  const float* s = (c8 < 256) ? (x + (size_t)r * 2048 + (size_t)c8 * 8)
                              : (h + (size_t)r * 2048 + (size_t)(c8 - 256) * 8);
  const float4 v0 = ((const float4*)s)[0];
  const float4 v1 = ((const float4*)s)[1];
  const uint32_t p0 = (uint32_t)f2bf(v0.x) | ((uint32_t)f2bf(v0.y) << 16);
  const uint32_t p1 = (uint32_t)f2bf(v0.z) | ((uint32_t)f2bf(v0.w) << 16);
  const uint32_t p2 = (uint32_t)f2bf(v1.x) | ((uint32_t)f2bf(v1.y) << 16);
  const uint32_t p3 = (uint32_t)f2bf(v1.z) | ((uint32_t)f2bf(v1.w) << 16);
  *(uint4*)(A1 + tid * 8) = make_uint4(p0, p1, p2, p3);
}

// ---- transpose W [4096][2048] f32 -> dst [2048][4096] bf16 ----
__global__ void transpose_w_kernel(const float* __restrict__ src, u16* __restrict__ dst) {
  __shared__ float tile[32][33];
  const int n0 = blockIdx.x * 32;
  const int k0 = blockIdx.y * 32;
  const int tx = threadIdx.x, ty = threadIdx.y;
#pragma unroll
  for (int i = 0; i < 32; i += 8)
    tile[ty + i][tx] = src[(size_t)(k0 + ty + i) * 2048 + n0 + tx];
  __syncthreads();
#pragma unroll
  for (int i = 0; i < 32; i += 8)
    dst[(size_t)(n0 + ty + i) * 4096 + k0 + tx] = f2bf(tile[tx][ty + i]);
}

// ---- 256x256x64 8-phase GEMM (T2+T3+T4+T5). MODE 0: z|r gates; MODE 1: n gate ----
template <int MODE>
__global__ __launch_bounds__(512, 2) void gemm8p_kernel(
    const u16* __restrict__ A1, const u16* __restrict__ RH,
    const u16* __restrict__ Bt, const float* __restrict__ h_prev,
    const float* __restrict__ bias0, const float* __restrict__ bias1,
    u16* __restrict__ Z, u16* __restrict__ RHout, float* __restrict__ out) {
  extern __shared__ char smem[];   // [0,64K): A slots (parity*2+half)<<14 ; [64K,128K): B slots
  constexpr int NBN = (MODE == 0) ? 16 : 8;

  const int t = threadIdx.x;
  const int l = t & 63, w = t >> 6;
  const int wm = w >> 2, wn = w & 3;
  const int lr = l & 15, khi = l >> 4;

  // XCD-aware bijective swizzle (nwg % 8 == 0)
  const int nwg = 32 * NBN;
  int bid = blockIdx.x;
  bid = (bid & 7) * (nwg >> 3) + (bid >> 3);
  const int bm = bid / NBN, bn = bid % NBN;
  const int arow = bm * 256;
  const int brow = bn * 256;

  char* Abase = smem;
  char* Bbase = smem + 65536;

  auto stageA = [&](int T, int half) {
    const u16* src;
    size_t ld;
    if constexpr (MODE == 1) {
      if (T >= 32) { src = RH + (size_t)(arow + half * 128) * HID + (T * 64 - 2048); ld = HID; }
      else         { src = A1 + (size_t)(arow + half * 128) * COMB + T * 64;         ld = COMB; }
    } else {
      src = A1 + (size_t)(arow + half * 128) * COMB + T * 64; ld = COMB;
    }
    stage_half(src, ld, Abase + (((T & 1) * 2 + half) << 14), w, l);
  };
  auto stageB = [&](int T, int half) {
    stage_half(Bt + (size_t)(brow + half * 128) * COMB + T * 64, COMB,
               Bbase + (((T & 1) * 2 + half) << 14), w, l);
  };

  // Prologue: tile0 {A0,A1,B0,B1} + tile1 {A0,A1,B0}; drain to 6 outstanding (=3 halves).
  stageA(0, 0); stageA(0, 1); stageB(0, 0); stageB(0, 1);
  stageA(1, 0); stageA(1, 1); stageB(1, 0);
  VM6();
  BARRIER();

  f32x4 acc[8][4] = {};
  bf16x8 af[8][2], bb[4][2];

#pragma unroll 2
  for (int j = 0; j < NT; ++j) {
    const int p = j & 1;
    const char* Ah = Abase + (((p << 1) + wm) << 14);          // wave's A half slot
    const char* Bh = Bbase + (((p << 1) + (wn >> 1)) << 14);   // wave's B half slot
    const int bro = (wn & 1) * 64;

    // ---- phase 0: read ALL A frags + B nh0; stage B1(j+1); MFMA quad (0,0)
#pragma unroll
    for (int m = 0; m < 8; ++m)
#pragma unroll
      for (int ks = 0; ks < 2; ++ks)
        af[m][ks] = rd(Ah, m * 16 + lr, ks * 32 + khi * 8);
#pragma unroll
    for (int n = 0; n < 2; ++n)
#pragma unroll
      for (int ks = 0; ks < 2; ++ks)
        bb[n][ks] = rd(Bh, bro + n * 16 + lr, ks * 32 + khi * 8);
    if (j < NT - 1) stageB(j + 1, 1);
    BARRIER();
    LGKM0();
    __builtin_amdgcn_s_setprio(1);
    MFMA_QUAD(0, 0);
    __builtin_amdgcn_s_setprio(0);
    BARRIER();

    // ---- phase 1: stage A0(j+2); MFMA quad (1,0)
    if (j < NT - 2) stageA(j + 2, 0);
    BARRIER();
    __builtin_amdgcn_s_setprio(1);
    MFMA_QUAD(1, 0);
    __builtin_amdgcn_s_setprio(0);
    BARRIER();

    // ---- phase 2: read B nh1; stage A1(j+2); MFMA quad (1,1)
#pragma unroll
    for (int n = 2; n < 4; ++n)
#pragma unroll
      for (int ks = 0; ks < 2; ++ks)
        bb[n][ks] = rd(Bh, bro + n * 16 + lr, ks * 32 + khi * 8);
    if (j < NT - 2) stageA(j + 2, 1);
    BARRIER();
    LGKM0();
    __builtin_amdgcn_s_setprio(1);
    MFMA_QUAD(1, 1);
    __builtin_amdgcn_s_setprio(0);
    BARRIER();

    // ---- phase 3: stage B0(j+2); MFMA quad (0,1); counted vmcnt at tile boundary
    if (j < NT - 2) stageB(j + 2, 0);
    BARRIER();
    __builtin_amdgcn_s_setprio(1);
    MFMA_QUAD(0, 1);
    __builtin_amdgcn_s_setprio(0);
    if (j < NT - 2) { VM6(); } else { VM0(); }
    BARRIER();
  }

  // ---- epilogue
  const int r0g = arow + wm * 128 + khi * 4;
  const int c0g = brow + wn * 64 + lr;
  if constexpr (MODE == 0) {
    const bool isZ = (bn < 8);
    const float* bias = isZ ? bias0 : bias1;
#pragma unroll
    for (int n = 0; n < 4; ++n) {
      const int colg = c0g + n * 16;
      const int col = isZ ? colg : (colg - 2048);
      const float bv = bias[col];
#pragma unroll
      for (int m = 0; m < 8; ++m)
#pragma unroll
        for (int r = 0; r < 4; ++r) {
          const int row = r0g + m * 16 + r;
          const size_t idx = (size_t)row * HID + col;
          const float v = acc[m][n][r] + bv;
          if (isZ) {
            Z[idx] = f2bf(fsigmoid(v));
          } else {
            const float rv = fsigmoid(v);
            RHout[idx] = f2bf(rv * h_prev[idx]);
          }
        }
    }
  } else {
#pragma unroll
    for (int n = 0; n < 4; ++n) {
      const int col = c0g + n * 16;
      const float bv = bias0[col];
#pragma unroll
      for (int m = 0; m < 8; ++m)
#pragma unroll
        for (int r = 0; r < 4; ++r) {
          const int row = r0g + m * 16 + r;
          const size_t idx = (size_t)row * HID + col;
          const float nn = ftanh(acc[m][n][r] + bv);
          const float zz = bf2f(Z[idx]);
          const float hp = h_prev[idx];
          out[idx] = (1.0f - zz) * hp + zz * nn;
        }
    }
  }
}

extern "C" void kernel_launch(void* const* d_in, const int* in_sizes, int n_in,
                              void* d_out, int out_size, void* d_ws, size_t ws_size,
                              hipStream_t stream) {
  const float* x  = (const float*)d_in[0];
  const float* h  = (const float*)d_in[1];
  const float* Wz = (const float*)d_in[2];
  const float* bz = (const float*)d_in[3];
  const float* Wr = (const float*)d_in[4];
  const float* br = (const float*)d_in[5];
  const float* Wn = (const float*)d_in[6];
  const float* bn = (const float*)d_in[7];
  float* out = (float*)d_out;

  char* ws = (char*)d_ws;
  u16* A1  = (u16*)(ws);                    // 8192*4096*2 = 67108864
  u16* RH  = (u16*)(ws + 67108864);         // 8192*2048*2 = 33554432
  u16* B1t = (u16*)(ws + 100663296);        // 4096*4096*2 = 33554432  ([Wz;Wr]^T)
  u16* B2t = (u16*)(ws + 134217728);        // 2048*4096*2 = 16777216  (Wn^T)
  u16* Z   = (u16*)(ws + 150994944);        // 8192*2048*2 = 33554432

  (void)hipFuncSetAttribute(reinterpret_cast<const void*>(&gemm8p_kernel<0>),
                            hipFuncAttributeMaxDynamicSharedMemorySize, 131072);
  (void)hipFuncSetAttribute(reinterpret_cast<const void*>(&gemm8p_kernel<1>),
                            hipFuncAttributeMaxDynamicSharedMemorySize, 131072);

  pack_A_kernel<<<16384, 256, 0, stream>>>(x, h, A1);
  dim3 tb(32, 8);
  transpose_w_kernel<<<dim3(64, 128), tb, 0, stream>>>(Wz, B1t);
  transpose_w_kernel<<<dim3(64, 128), tb, 0, stream>>>(Wr, B1t + (size_t)2048 * 4096);
  transpose_w_kernel<<<dim3(64, 128), tb, 0, stream>>>(Wn, B2t);

  gemm8p_kernel<0><<<dim3(512), 512, 131072, stream>>>(A1, nullptr, B1t, h, bz, br, Z, RH, nullptr);
  gemm8p_kernel<1><<<dim3(256), 512, 131072, stream>>>(A1, RH, B2t, h, bn, nullptr, Z, nullptr, out);
}